// Round 10
// baseline (575.181 us; speedup 1.0000x reference)
//
#include <hip/hip_runtime.h>
#include <hip/hip_bf16.h>
#include <hip/hip_cooperative_groups.h>
#include <math.h>

namespace cg = cooperative_groups;

#define NROW 6144
#define LRELU_ALPHA 0.2f
#define MAXD 128   // padded CSR row capacity; mean nnz 62.4, sigma 7.8 -> ~8.3 sigma headroom

typedef __attribute__((ext_vector_type(8))) __bf16 bf16x8;
typedef __attribute__((ext_vector_type(16))) float f32x16;

// ---------------- prep_csr: register-lean CSR build (blocks 0..6143) +
// weight split/transpose (next 672) + wsa/wna dots (last 4). Register-light
// only — deliberately NO MFMA code in this kernel (mega1 regalloc lesson).
__global__ __launch_bounds__(256) void prep_csr(
    const float* __restrict__ adj, const float* __restrict__ Mm,
    int* __restrict__ cnt, int* __restrict__ cidx, float* __restrict__ cmval,
    const float* __restrict__ W1, const float* __restrict__ W2, const float* __restrict__ W3,
    __bf16* __restrict__ w1h, __bf16* __restrict__ w1l,
    __bf16* __restrict__ w2h, __bf16* __restrict__ w2l,
    __bf16* __restrict__ w3h, __bf16* __restrict__ w3l,
    const float* __restrict__ as1, const float* __restrict__ an1,
    const float* __restrict__ as2, const float* __restrict__ an2,
    const float* __restrict__ as3, const float* __restrict__ an3,
    float* __restrict__ wsa1, float* __restrict__ wna1,
    float* __restrict__ wsa2, float* __restrict__ wna2,
    float* __restrict__ wsa3, float* __restrict__ wna3) {
  int b = blockIdx.x;
  if (b < NROW) {
    const int row = b;
    const int wv = threadIdx.x >> 6, lane = threadIdx.x & 63;
    __shared__ int wtot[4];
    __shared__ int jsh[MAXD];
    const float4* arow = (const float4*)(adj + (size_t)row * NROW);
    uint32_t mask = 0;
#pragma unroll
    for (int it = 0; it < 6; ++it) {
      float4 a = arow[wv * 384 + it * 64 + lane];
      uint32_t q = (a.x > 0.f ? 1u : 0u) | (a.y > 0.f ? 2u : 0u) |
                   (a.z > 0.f ? 4u : 0u) | (a.w > 0.f ? 8u : 0u);
      mask |= q << (it * 4);
    }
    const int pc = __popc(mask);
    int pre = pc;
#pragma unroll
    for (int off = 1; off < 64; off <<= 1) {
      int t = __shfl_up(pre, off);
      if (lane >= off) pre += t;
    }
    if (lane == 63) wtot[wv] = pre;
    __syncthreads();
    int base = pre - pc;
    for (int w = 0; w < wv; ++w) base += wtot[w];
    const int total = min(wtot[0] + wtot[1] + wtot[2] + wtot[3], MAXD);
    uint32_t m = mask;
    int p = base;
    const int cbase = wv * 1536 + lane * 4;
    while (m) {
      int bit = __ffs(m) - 1;
      m &= m - 1;
      if (p < MAXD) jsh[p] = cbase + ((bit >> 2) << 8) + (bit & 3);
      ++p;
    }
    __syncthreads();
    const float* mrow = Mm + (size_t)row * NROW;
    for (int k = threadIdx.x; k < total; k += 256) {
      int j = jsh[k];
      cidx[(size_t)row * MAXD + k] = j;
      cmval[(size_t)row * MAXD + k] = mrow[j];
    }
    if (threadIdx.x == 0) cnt[row] = total;
    return;
  }
  b -= NROW;
  if (b < 672) {
    int idx = b * 256 + threadIdx.x;
    const float* W; __bf16 *wh, *wl; int K, D;
    if (idx < 131072) { W = W1; wh = w1h; wl = w1l; K = 512; D = 256; }
    else if (idx < 163840) { idx -= 131072; W = W2; wh = w2h; wl = w2l; K = 256; D = 128; }
    else { idx -= 163840; if (idx >= 8192) return; W = W3; wh = w3h; wl = w3l; K = 128; D = 64; }
    int k = idx / D, d = idx - k * D;
    float v = W[idx];
    __bf16 h = (__bf16)v;
    wh[(size_t)d * K + k] = h;
    wl[(size_t)d * K + k] = (__bf16)(v - (float)h);
    return;
  }
  int t = (b - 672) * 256 + threadIdx.x;
  if (t < 512) {
    float s = 0.f, n = 0.f;
    for (int d = 0; d < 256; ++d) { float w = W1[t * 256 + d]; s = fmaf(w, as1[d], s); n = fmaf(w, an1[d], n); }
    wsa1[t] = s; wna1[t] = n;
  } else if (t < 768) {
    int k = t - 512;
    float s = 0.f, n = 0.f;
    for (int d = 0; d < 128; ++d) { float w = W2[k * 128 + d]; s = fmaf(w, as2[d], s); n = fmaf(w, an2[d], n); }
    wsa2[k] = s; wna2[k] = n;
  } else if (t < 896) {
    int k = t - 768;
    float s = 0.f, n = 0.f;
    for (int d = 0; d < 64; ++d) { float w = W3[k * 64 + d]; s = fmaf(w, as3[d], s); n = fmaf(w, an3[d], n); }
    wsa3[k] = s; wna3[k] = n;
  }
}

// ---------------- GEMM body (split-bf16 MFMA + fused sv/nv), C/Cb nullable
__device__ __forceinline__ void gemm_body(int bx, int by,
                                          const float* __restrict__ A,
                                          const __bf16* __restrict__ Bth,
                                          const __bf16* __restrict__ Btl,
                                          const float* __restrict__ wsa,
                                          const float* __restrict__ wna,
                                          float* __restrict__ sv,
                                          float* __restrict__ nv,
                                          float* __restrict__ C,
                                          __bf16* __restrict__ Cb, int K, int D) {
  const int wv = threadIdx.x >> 6, lane = threadIdx.x & 63;
  const int l31 = lane & 31, lh = lane >> 5;
  const int ib = bx * 64 + (wv >> 1) * 32;
  const int jb = by * 64 + (wv & 1) * 32;
  const float* Arow = A + (size_t)(ib + l31) * K + lh * 8;
  const __bf16* Bh = Bth + (size_t)(jb + l31) * K + lh * 8;
  const __bf16* Bl = Btl + (size_t)(jb + l31) * K + lh * 8;
  const bool do_sn = (by == 0) && ((wv & 1) == 0);
  f32x16 acc;
#pragma unroll
  for (int r = 0; r < 16; ++r) acc[r] = 0.f;
  float ss = 0.f, nn = 0.f;
  for (int k = 0; k < K; k += 16) {
    float4 a0 = *(const float4*)(Arow + k);
    float4 a1 = *(const float4*)(Arow + k + 4);
    bf16x8 bh = *(const bf16x8*)(Bh + k);
    bf16x8 bl = *(const bf16x8*)(Bl + k);
    float av[8] = {a0.x, a0.y, a0.z, a0.w, a1.x, a1.y, a1.z, a1.w};
    if (do_sn) {
      float4 s0 = *(const float4*)(wsa + k + lh * 8);
      float4 s1 = *(const float4*)(wsa + k + lh * 8 + 4);
      float4 n0 = *(const float4*)(wna + k + lh * 8);
      float4 n1 = *(const float4*)(wna + k + lh * 8 + 4);
      ss = fmaf(av[0], s0.x, ss); ss = fmaf(av[1], s0.y, ss);
      ss = fmaf(av[2], s0.z, ss); ss = fmaf(av[3], s0.w, ss);
      ss = fmaf(av[4], s1.x, ss); ss = fmaf(av[5], s1.y, ss);
      ss = fmaf(av[6], s1.z, ss); ss = fmaf(av[7], s1.w, ss);
      nn = fmaf(av[0], n0.x, nn); nn = fmaf(av[1], n0.y, nn);
      nn = fmaf(av[2], n0.z, nn); nn = fmaf(av[3], n0.w, nn);
      nn = fmaf(av[4], n1.x, nn); nn = fmaf(av[5], n1.y, nn);
      nn = fmaf(av[6], n1.z, nn); nn = fmaf(av[7], n1.w, nn);
    }
    bf16x8 ah, al;
#pragma unroll
    for (int t = 0; t < 8; ++t) {
      __bf16 h = (__bf16)av[t];
      ah[t] = h;
      al[t] = (__bf16)(av[t] - (float)h);
    }
    acc = __builtin_amdgcn_mfma_f32_32x32x16_bf16(ah, bh, acc, 0, 0, 0);
    acc = __builtin_amdgcn_mfma_f32_32x32x16_bf16(ah, bl, acc, 0, 0, 0);
    acc = __builtin_amdgcn_mfma_f32_32x32x16_bf16(al, bh, acc, 0, 0, 0);
  }
  if (do_sn) {
    ss += __shfl_xor(ss, 32);
    nn += __shfl_xor(nn, 32);
    if (lh == 0) { sv[ib + l31] = ss; nv[ib + l31] = nn; }
  }
#pragma unroll
  for (int r = 0; r < 16; ++r) {
    int rowi = (r & 3) + 8 * (r >> 2) + 4 * lh;
    if (C)  C[(size_t)(ib + rowi) * D + jb + l31] = acc[r];
    if (Cb) Cb[(size_t)(ib + rowi) * D + jb + l31] = (__bf16)acc[r];
  }
}

// ---------------- attention body (CSR softmax + gather + elu; optional norm)
template <int D, int WPR, bool BF16G, bool NORM>
__device__ __forceinline__ void attn_body(int blk,
                                          const float* __restrict__ h,
                                          const __bf16* __restrict__ hb,
                                          const int* __restrict__ cnt,
                                          const int* __restrict__ cidx,
                                          const float* __restrict__ cmval,
                                          const float* __restrict__ sv,
                                          const float* __restrict__ nv,
                                          float* __restrict__ out,
                                          __bf16* __restrict__ zbp,
                                          float (*ws)[MAXD], int (*js)[MAXD]) {
  constexpr int RPB = 4 / WPR;
  constexpr int CW = D / WPR;
  constexpr int NQ = BF16G ? 2 : CW / 64;
  const int wv = threadIdx.x >> 6, lane = threadIdx.x & 63;
  const int row = blk * RPB + wv / WPR;
  const int half = wv % WPR;
  const int c = cnt[row];
  const float si = sv[row];
  const size_t cb = (size_t)row * MAXD;

  float e0 = -1e30f, e1 = -1e30f;
  int j0 = 0, j1 = 0;
  if (lane < c) {
    j0 = cidx[cb + lane];
    float v = (si + nv[j0]) * cmval[cb + lane];
    e0 = v > 0.f ? v : LRELU_ALPHA * v;
  }
  if (lane + 64 < c) {
    j1 = cidx[cb + lane + 64];
    float v = (si + nv[j1]) * cmval[cb + lane + 64];
    e1 = v > 0.f ? v : LRELU_ALPHA * v;
  }
  float mx = fmaxf(e0, e1);
#pragma unroll
  for (int off = 32; off; off >>= 1) mx = fmaxf(mx, __shfl_xor(mx, off));
  float w0 = lane < c ? __expf(e0 - mx) : 0.f;
  float w1 = lane + 64 < c ? __expf(e1 - mx) : 0.f;
  float s = w0 + w1;
#pragma unroll
  for (int off = 32; off; off >>= 1) s += __shfl_xor(s, off);
  const float inv = 1.f / s;
  ws[wv][lane] = w0 * inv;
  ws[wv][lane + 64] = w1 * inv;
  js[wv][lane] = j0;
  js[wv][lane + 64] = j1;
  // intra-wave LDS write->read: single-wave coherence, no barrier
  const int cbase = half * CW;
  float acc[NQ];
#pragma unroll
  for (int q = 0; q < NQ; ++q) acc[q] = 0.f;
  if (BF16G) {
#pragma unroll 8
    for (int k = 0; k < c; ++k) {
      const float wk = ws[wv][k];
      const uint32_t* hr = (const uint32_t*)(hb + (size_t)js[wv][k] * D + cbase);
      uint32_t v = hr[lane];
      acc[0] = fmaf(wk, __uint_as_float(v << 16), acc[0]);
      acc[1] = fmaf(wk, __uint_as_float(v & 0xffff0000u), acc[1]);
    }
    float2 o;
    o.x = acc[0] > 0.f ? acc[0] : expm1f(acc[0]);
    o.y = acc[1] > 0.f ? acc[1] : expm1f(acc[1]);
    *(float2*)(out + (size_t)row * D + cbase + lane * 2) = o;
  } else {
#pragma unroll 8
    for (int k = 0; k < c; ++k) {
      const float wk = ws[wv][k];
      const float* hr = h + (size_t)js[wv][k] * D + cbase;
#pragma unroll
      for (int q = 0; q < NQ; ++q) acc[q] = fmaf(wk, hr[lane + q * 64], acc[q]);
    }
    if (!NORM) {
#pragma unroll
      for (int q = 0; q < NQ; ++q) {
        float a = acc[q];
        out[(size_t)row * D + cbase + lane + q * 64] = a > 0.f ? a : expm1f(a);
      }
    } else {
      float a = acc[0];
      a = a > 0.f ? a : expm1f(a);
      float sq = a * a;
#pragma unroll
      for (int off = 32; off; off >>= 1) sq += __shfl_xor(sq, off);
      float zv = a / fmaxf(sqrtf(sq), 1e-12f);
      out[(size_t)row * 64 + lane] = zv;
      zbp[(size_t)row * 64 + lane] = (__bf16)zv;
    }
  }
}

// ---------------- decoder body: sigmoid(z@z^T) 64x64 tile via bf16 MFMA
__device__ __forceinline__ void decoder_body(int bj, int bi,
                                             const __bf16* __restrict__ zb,
                                             float* __restrict__ out) {
  const int wv = threadIdx.x >> 6, lane = threadIdx.x & 63;
  const int ib = bi * 64 + (wv >> 1) * 32;
  const int jb = bj * 64 + (wv & 1) * 32;
  const int l31 = lane & 31, lh = lane >> 5;
  const __bf16* Arow = zb + (size_t)(ib + l31) * 64 + lh * 8;
  const __bf16* Brow = zb + (size_t)(jb + l31) * 64 + lh * 8;
  f32x16 acc;
#pragma unroll
  for (int r = 0; r < 16; ++r) acc[r] = 0.f;
#pragma unroll
  for (int kk = 0; kk < 4; ++kk) {
    bf16x8 af = *(const bf16x8*)(Arow + kk * 16);
    bf16x8 bfv = *(const bf16x8*)(Brow + kk * 16);
    acc = __builtin_amdgcn_mfma_f32_32x32x16_bf16(af, bfv, acc, 0, 0, 0);
  }
#pragma unroll
  for (int r = 0; r < 16; ++r) {
    int rowi = (r & 3) + 8 * (r >> 2) + 4 * lh;
    float v = 1.f / (1.f + __expf(-acc[r]));
    out[(size_t)(ib + rowi) * NROW + jb + l31] = v;
  }
}

// ---------------- cooperative pipeline: gemm1..attn3+norm, decoder.
// grid-stride phases + grid.sync() -> zero inter-dispatch drains, one
// profiled dispatch with aggregate counters.
__global__ __launch_bounds__(256) void gat_all(
    const float* __restrict__ x,
    const __bf16* __restrict__ w1h, const __bf16* __restrict__ w1l,
    const __bf16* __restrict__ w2h, const __bf16* __restrict__ w2l,
    const __bf16* __restrict__ w3h, const __bf16* __restrict__ w3l,
    const float* __restrict__ wsa1, const float* __restrict__ wna1,
    const float* __restrict__ wsa2, const float* __restrict__ wna2,
    const float* __restrict__ wsa3, const float* __restrict__ wna3,
    const int* __restrict__ cct, const int* __restrict__ cix,
    const float* __restrict__ cmv,
    float* __restrict__ sv, float* __restrict__ nv,
    float* __restrict__ hA, float* __restrict__ hB,
    __bf16* __restrict__ hAb,
    float* __restrict__ z, __bf16* __restrict__ zb,
    float* __restrict__ out) {
  cg::grid_group grid = cg::this_grid();
  const int G = gridDim.x;
  __shared__ float sws[4][MAXD];
  __shared__ int sjs[4][MAXD];

  // L1: h1 = x@W1 (bf16 copy) + sv/nv
  for (int j = blockIdx.x; j < 384; j += G)
    gemm_body(j >> 2, j & 3, x, w1h, w1l, wsa1, wna1, sv, nv, nullptr, hAb, 512, 256);
  grid.sync();
  for (int j = blockIdx.x; j < 3072; j += G)
    attn_body<256, 2, true, false>(j, nullptr, hAb, cct, cix, cmv, sv, nv, hB, nullptr, sws, sjs);
  grid.sync();
  // L2
  for (int j = blockIdx.x; j < 192; j += G)
    gemm_body(j >> 1, j & 1, hB, w2h, w2l, wsa2, wna2, sv, nv, nullptr, hAb, 256, 128);
  grid.sync();
  for (int j = blockIdx.x; j < 1536; j += G)
    attn_body<128, 1, true, false>(j, nullptr, hAb, cct, cix, cmv, sv, nv, hB, nullptr, sws, sjs);
  grid.sync();
  // L3
  for (int j = blockIdx.x; j < 96; j += G)
    gemm_body(j, 0, hB, w3h, w3l, wsa3, wna3, sv, nv, hA, nullptr, 128, 64);
  grid.sync();
  for (int j = blockIdx.x; j < 1536; j += G)
    attn_body<64, 1, false, true>(j, hA, nullptr, cct, cix, cmv, sv, nv, z, zb, sws, sjs);
  grid.sync();
  // decoder
  for (int j = blockIdx.x; j < 9216; j += G)
    decoder_body(j % 96, j / 96, zb, out);
}

extern "C" void kernel_launch(void* const* d_in, const int* in_sizes, int n_in,
                              void* d_out, int out_size, void* d_ws, size_t ws_size,
                              hipStream_t stream) {
  const float* x   = (const float*)d_in[0];
  const float* adj = (const float*)d_in[1];
  const float* Mm  = (const float*)d_in[2];
  const float* W1  = (const float*)d_in[3];
  const float* as1 = (const float*)d_in[4];
  const float* an1 = (const float*)d_in[5];
  const float* W2  = (const float*)d_in[6];
  const float* as2 = (const float*)d_in[7];
  const float* an2 = (const float*)d_in[8];
  const float* W3  = (const float*)d_in[9];
  const float* as3 = (const float*)d_in[10];
  const float* an3 = (const float*)d_in[11];

  float* out = (float*)d_out;
  float* z = out + (size_t)NROW * NROW;

  float* wsp = (float*)d_ws;
  float* hA   = wsp;                          // [N,256] max (f32, layer-3 gather)
  float* hB   = hA + (size_t)NROW * 256;      // [N,256] max (attn outputs)
  float* sv   = hB + (size_t)NROW * 256;      // [N]
  float* nv   = sv + NROW;                    // [N]
  float* cmv  = nv + NROW;                    // [N,MAXD]
  int*   cix  = (int*)(cmv + (size_t)NROW * MAXD);  // [N,MAXD]
  int*   cct  = cix + (size_t)NROW * MAXD;    // [N]
  __bf16* zb  = (__bf16*)(cct + NROW);        // [N,64]
  __bf16* w1h = zb + (size_t)NROW * 64;       // split/transposed weights
  __bf16* w1l = w1h + 512 * 256;
  __bf16* w2h = w1l + 512 * 256;
  __bf16* w2l = w2h + 256 * 128;
  __bf16* w3h = w2l + 256 * 128;
  __bf16* w3l = w3h + 128 * 64;
  float* wsa1 = (float*)(w3l + 128 * 64);     // wsa/wna vectors
  float* wna1 = wsa1 + 512;
  float* wsa2 = wna1 + 512;
  float* wna2 = wsa2 + 256;
  float* wsa3 = wna2 + 256;
  float* wna3 = wsa3 + 128;
  __bf16* hAb = (__bf16*)(wna3 + 128);        // [N,256] bf16 gather copy

  dim3 b256(256);

  // 1. layer-invariant prep: CSR + weight splits + wsa/wna dots
  prep_csr<<<dim3(NROW + 676), b256, 0, stream>>>(
      adj, Mm, cct, cix, cmv, W1, W2, W3, w1h, w1l, w2h, w2l, w3h, w3l,
      as1, an1, as2, an2, as3, an3, wsa1, wna1, wsa2, wna2, wsa3, wna3);

  // 2. cooperative GAT+decoder pipeline (grid sized to guaranteed co-residency)
  int nb = 0;
  (void)hipOccupancyMaxActiveBlocksPerMultiprocessor(&nb, gat_all, 256, 0);
  if (nb < 1) nb = 1;
  if (nb > 8) nb = 8;
  int G = nb * 256;  // 256 CUs on MI355X

  void* args[] = {(void*)&x,
                  (void*)&w1h, (void*)&w1l, (void*)&w2h, (void*)&w2l,
                  (void*)&w3h, (void*)&w3l,
                  (void*)&wsa1, (void*)&wna1, (void*)&wsa2, (void*)&wna2,
                  (void*)&wsa3, (void*)&wna3,
                  (void*)&cct, (void*)&cix, (void*)&cmv,
                  (void*)&sv, (void*)&nv, (void*)&hA, (void*)&hB, (void*)&hAb,
                  (void*)&z, (void*)&zb, (void*)&out};
  (void)hipLaunchCooperativeKernel(gat_all, dim3(G), b256, args, 0, stream);
}

// Round 11
// 190.547 us; speedup vs baseline: 3.0186x; 3.0186x over previous
//
#include <hip/hip_runtime.h>
#include <hip/hip_bf16.h>
#include <math.h>

#define NROW 6144
#define LRELU_ALPHA 0.2f
#define MAXD 128   // padded CSR row capacity; mean nnz 62.4, sigma 7.8 -> ~8.3 sigma headroom

typedef __attribute__((ext_vector_type(8))) __bf16 bf16x8;
typedef __attribute__((ext_vector_type(16))) float f32x16;

// ---------------- tiny prep: weight split/transpose (blocks 0..671) + wsa/wna dots
__global__ __launch_bounds__(256) void prep_small(
    const float* __restrict__ W1, const float* __restrict__ W2, const float* __restrict__ W3,
    __bf16* __restrict__ w1h, __bf16* __restrict__ w1l,
    __bf16* __restrict__ w2h, __bf16* __restrict__ w2l,
    __bf16* __restrict__ w3h, __bf16* __restrict__ w3l,
    const float* __restrict__ as1, const float* __restrict__ an1,
    const float* __restrict__ as2, const float* __restrict__ an2,
    const float* __restrict__ as3, const float* __restrict__ an3,
    float* __restrict__ wsa1, float* __restrict__ wna1,
    float* __restrict__ wsa2, float* __restrict__ wna2,
    float* __restrict__ wsa3, float* __restrict__ wna3) {
  int b = blockIdx.x;
  if (b < 672) {
    int idx = b * 256 + threadIdx.x;
    const float* W; __bf16 *wh, *wl; int K, D;
    if (idx < 131072) { W = W1; wh = w1h; wl = w1l; K = 512; D = 256; }
    else if (idx < 163840) { idx -= 131072; W = W2; wh = w2h; wl = w2l; K = 256; D = 128; }
    else { idx -= 163840; if (idx >= 8192) return; W = W3; wh = w3h; wl = w3l; K = 128; D = 64; }
    int k = idx / D, d = idx - k * D;
    float v = W[idx];
    __bf16 h = (__bf16)v;
    wh[(size_t)d * K + k] = h;
    wl[(size_t)d * K + k] = (__bf16)(v - (float)h);
    return;
  }
  int t = (b - 672) * 256 + threadIdx.x;
  if (t < 512) {
    float s = 0.f, n = 0.f;
    for (int d = 0; d < 256; ++d) { float w = W1[t * 256 + d]; s = fmaf(w, as1[d], s); n = fmaf(w, an1[d], n); }
    wsa1[t] = s; wna1[t] = n;
  } else if (t < 768) {
    int k = t - 512;
    float s = 0.f, n = 0.f;
    for (int d = 0; d < 128; ++d) { float w = W2[k * 128 + d]; s = fmaf(w, as2[d], s); n = fmaf(w, an2[d], n); }
    wsa2[k] = s; wna2[k] = n;
  } else if (t < 896) {
    int k = t - 768;
    float s = 0.f, n = 0.f;
    for (int d = 0; d < 64; ++d) { float w = W3[k * 64 + d]; s = fmaf(w, as3[d], s); n = fmaf(w, an3[d], n); }
    wsa3[k] = s; wna3[k] = n;
  }
}

// ---------------- GEMM: C[N,D] = A[N,K] @ B[K,D] via split-bf16 MFMA
// + fused sv/nv (s = h@a_s = A@(W@a_s), exact algebra); C/Cb nullable.
__global__ __launch_bounds__(256) void gemm_mfma(const float* __restrict__ A,
                                                 const __bf16* __restrict__ Bth,
                                                 const __bf16* __restrict__ Btl,
                                                 const float* __restrict__ wsa,
                                                 const float* __restrict__ wna,
                                                 float* __restrict__ sv,
                                                 float* __restrict__ nv,
                                                 float* __restrict__ C,
                                                 __bf16* __restrict__ Cb, int K, int D) {
  const int wv = threadIdx.x >> 6, lane = threadIdx.x & 63;
  const int l31 = lane & 31, lh = lane >> 5;
  const int ib = blockIdx.x * 64 + (wv >> 1) * 32;
  const int jb = blockIdx.y * 64 + (wv & 1) * 32;
  const float* Arow = A + (size_t)(ib + l31) * K + lh * 8;
  const __bf16* Bh = Bth + (size_t)(jb + l31) * K + lh * 8;
  const __bf16* Bl = Btl + (size_t)(jb + l31) * K + lh * 8;
  const bool do_sn = (blockIdx.y == 0) && ((wv & 1) == 0);
  f32x16 acc;
#pragma unroll
  for (int r = 0; r < 16; ++r) acc[r] = 0.f;
  float ss = 0.f, nn = 0.f;
  for (int k = 0; k < K; k += 16) {
    float4 a0 = *(const float4*)(Arow + k);
    float4 a1 = *(const float4*)(Arow + k + 4);
    bf16x8 bh = *(const bf16x8*)(Bh + k);
    bf16x8 bl = *(const bf16x8*)(Bl + k);
    float av[8] = {a0.x, a0.y, a0.z, a0.w, a1.x, a1.y, a1.z, a1.w};
    if (do_sn) {
      float4 s0 = *(const float4*)(wsa + k + lh * 8);
      float4 s1 = *(const float4*)(wsa + k + lh * 8 + 4);
      float4 n0 = *(const float4*)(wna + k + lh * 8);
      float4 n1 = *(const float4*)(wna + k + lh * 8 + 4);
      ss = fmaf(av[0], s0.x, ss); ss = fmaf(av[1], s0.y, ss);
      ss = fmaf(av[2], s0.z, ss); ss = fmaf(av[3], s0.w, ss);
      ss = fmaf(av[4], s1.x, ss); ss = fmaf(av[5], s1.y, ss);
      ss = fmaf(av[6], s1.z, ss); ss = fmaf(av[7], s1.w, ss);
      nn = fmaf(av[0], n0.x, nn); nn = fmaf(av[1], n0.y, nn);
      nn = fmaf(av[2], n0.z, nn); nn = fmaf(av[3], n0.w, nn);
      nn = fmaf(av[4], n1.x, nn); nn = fmaf(av[5], n1.y, nn);
      nn = fmaf(av[6], n1.z, nn); nn = fmaf(av[7], n1.w, nn);
    }
    bf16x8 ah, al;
#pragma unroll
    for (int t = 0; t < 8; ++t) {
      __bf16 h = (__bf16)av[t];
      ah[t] = h;
      al[t] = (__bf16)(av[t] - (float)h);
    }
    acc = __builtin_amdgcn_mfma_f32_32x32x16_bf16(ah, bh, acc, 0, 0, 0);
    acc = __builtin_amdgcn_mfma_f32_32x32x16_bf16(ah, bl, acc, 0, 0, 0);
    acc = __builtin_amdgcn_mfma_f32_32x32x16_bf16(al, bh, acc, 0, 0, 0);
  }
  if (do_sn) {
    ss += __shfl_xor(ss, 32);
    nn += __shfl_xor(nn, 32);
    if (lh == 0) { sv[ib + l31] = ss; nv[ib + l31] = nn; }
  }
  // C/D layout: col = lane&31, row = (reg&3) + 8*(reg>>2) + 4*(lane>>5)
#pragma unroll
  for (int r = 0; r < 16; ++r) {
    int rowi = (r & 3) + 8 * (r >> 2) + 4 * lh;
    if (C)  C[(size_t)(ib + rowi) * D + jb + l31] = acc[r];
    if (Cb) Cb[(size_t)(ib + rowi) * D + jb + l31] = (__bf16)acc[r];
  }
}

// ---------------- attn1_fused: CSR build + masked softmax + PV for layer 1,
// one block per 2 rows. Register-lean scan (24-bit mask/lane, no MFMA in this
// kernel). Writes CSR (cnt/cidx/cmval) for layers 2/3 reuse. Deterministic.
__global__ __launch_bounds__(256) void attn1_fused(
    const float* __restrict__ adj, const float* __restrict__ Mm,
    const __bf16* __restrict__ hb,
    const float* __restrict__ sv, const float* __restrict__ nv,
    float* __restrict__ out,
    int* __restrict__ cnt, int* __restrict__ cidx, float* __restrict__ cmval) {
  const int wv = threadIdx.x >> 6, lane = threadIdx.x & 63;
  const int rp = blockIdx.x * 2;
  __shared__ int jsx[2][MAXD];
  __shared__ float msx[2][MAXD];
  __shared__ float wsx[4][MAXD];
  __shared__ int wtot[2][4];
  // phase S: scan both adjacency rows; each wave scans a quarter-row
  uint32_t mask[2];
  int pre[2], pc[2];
#pragma unroll
  for (int r = 0; r < 2; ++r) {
    const float4* arow = (const float4*)(adj + (size_t)(rp + r) * NROW);
    uint32_t mk = 0;
#pragma unroll
    for (int it = 0; it < 6; ++it) {
      float4 a = arow[wv * 384 + it * 64 + lane];
      uint32_t q = (uint32_t)(a.x > 0.f) | ((uint32_t)(a.y > 0.f) << 1) |
                   ((uint32_t)(a.z > 0.f) << 2) | ((uint32_t)(a.w > 0.f) << 3);
      mk |= q << (it * 4);
    }
    mask[r] = mk;
    pc[r] = __popc(mk);
    int p = pc[r];
#pragma unroll
    for (int off = 1; off < 64; off <<= 1) {
      int t = __shfl_up(p, off);
      if (lane >= off) p += t;
    }
    pre[r] = p;
    if (lane == 63) wtot[r][wv] = p;
  }
  __syncthreads();
  int tot[2];
#pragma unroll
  for (int r = 0; r < 2; ++r) {
    int base = pre[r] - pc[r];
    for (int w = 0; w < wv; ++w) base += wtot[r][w];
    tot[r] = min(wtot[r][0] + wtot[r][1] + wtot[r][2] + wtot[r][3], MAXD);
    uint32_t m = mask[r];
    int p = base;
    const int cb0 = wv * 1536 + lane * 4;
    while (m) {
      int bit = __ffs(m) - 1;
      m &= m - 1;
      if (p < MAXD) jsx[r][p] = cb0 + ((bit >> 2) << 8) + (bit & 3);
      ++p;
    }
  }
  __syncthreads();
  // phase M: parallel M gather + CSR writeout (layers 2/3 reuse)
#pragma unroll
  for (int r = 0; r < 2; ++r) {
    const float* mrow = Mm + (size_t)(rp + r) * NROW;
    for (int k = threadIdx.x; k < tot[r]; k += 256) {
      int j = jsx[r][k];
      float mval = mrow[j];
      msx[r][k] = mval;
      cidx[(size_t)(rp + r) * MAXD + k] = j;
      cmval[(size_t)(rp + r) * MAXD + k] = mval;
    }
  }
  if (threadIdx.x < 2) cnt[rp + threadIdx.x] = tot[threadIdx.x];
  __syncthreads();
  // phase A: softmax (waves 0,1 -> row0; 2,3 -> row1; each wave full softmax)
  const int mr = wv >> 1, half = wv & 1;
  const int row = rp + mr;
  const int c = tot[mr];
  const float si = sv[row];
  float e0 = -1e30f, e1 = -1e30f;
  if (lane < c) {
    float v = (si + nv[jsx[mr][lane]]) * msx[mr][lane];
    e0 = v > 0.f ? v : LRELU_ALPHA * v;
  }
  if (lane + 64 < c) {
    float v = (si + nv[jsx[mr][lane + 64]]) * msx[mr][lane + 64];
    e1 = v > 0.f ? v : LRELU_ALPHA * v;
  }
  float mx = fmaxf(e0, e1);
#pragma unroll
  for (int off = 32; off; off >>= 1) mx = fmaxf(mx, __shfl_xor(mx, off));
  float w0 = lane < c ? __expf(e0 - mx) : 0.f;
  float w1 = lane + 64 < c ? __expf(e1 - mx) : 0.f;
  float s = w0 + w1;
#pragma unroll
  for (int off = 32; off; off >>= 1) s += __shfl_xor(s, off);
  const float inv = 1.f / s;
  wsx[wv][lane] = w0 * inv;
  wsx[wv][lane + 64] = w1 * inv;
  // phase PV: bf16 gather, each wave half the columns (2 cols/lane)
  const int cbase = half * 128;
  float a0 = 0.f, a1 = 0.f;
#pragma unroll 8
  for (int k = 0; k < c; ++k) {
    const float wk = wsx[wv][k];
    const uint32_t* hr = (const uint32_t*)(hb + (size_t)jsx[mr][k] * 256 + cbase);
    uint32_t v = hr[lane];
    a0 = fmaf(wk, __uint_as_float(v << 16), a0);
    a1 = fmaf(wk, __uint_as_float(v & 0xffff0000u), a1);
  }
  float2 o;
  o.x = a0 > 0.f ? a0 : expm1f(a0);
  o.y = a1 > 0.f ? a1 : expm1f(a1);
  *(float2*)(out + (size_t)row * 256 + cbase + lane * 2) = o;
}

// ---------------- CSR masked-softmax attention + att@h + elu (layers 2/3)
// WPR waves per row (col-split). BF16G: gather from bf16 h, 2 cols/lane.
// NORM: fuse row-normalize (D=64, f32 gather only), emit z+zb.
template <int D, int WPR, bool BF16G, bool NORM>
__global__ __launch_bounds__(256) void attn_csr(const float* __restrict__ h,
                                                const __bf16* __restrict__ hb,
                                                const int* __restrict__ cnt,
                                                const int* __restrict__ cidx,
                                                const float* __restrict__ cmval,
                                                const float* __restrict__ sv,
                                                const float* __restrict__ nv,
                                                float* __restrict__ out,
                                                __bf16* __restrict__ zb) {
  constexpr int RPB = 4 / WPR;
  constexpr int CW = D / WPR;
  constexpr int NQ = BF16G ? 2 : CW / 64;
  __shared__ float ws[4][MAXD];
  __shared__ int js[4][MAXD];
  const int wv = threadIdx.x >> 6, lane = threadIdx.x & 63;
  const int row = blockIdx.x * RPB + wv / WPR;
  const int half = wv % WPR;
  const int c = cnt[row];
  const float si = sv[row];
  const size_t cb = (size_t)row * MAXD;

  float e0 = -1e30f, e1 = -1e30f;
  int j0 = 0, j1 = 0;
  if (lane < c) {
    j0 = cidx[cb + lane];
    float v = (si + nv[j0]) * cmval[cb + lane];
    e0 = v > 0.f ? v : LRELU_ALPHA * v;
  }
  if (lane + 64 < c) {
    j1 = cidx[cb + lane + 64];
    float v = (si + nv[j1]) * cmval[cb + lane + 64];
    e1 = v > 0.f ? v : LRELU_ALPHA * v;
  }
  float mx = fmaxf(e0, e1);
#pragma unroll
  for (int off = 32; off; off >>= 1) mx = fmaxf(mx, __shfl_xor(mx, off));
  float w0 = lane < c ? __expf(e0 - mx) : 0.f;
  float w1 = lane + 64 < c ? __expf(e1 - mx) : 0.f;
  float s = w0 + w1;
#pragma unroll
  for (int off = 32; off; off >>= 1) s += __shfl_xor(s, off);
  const float inv = 1.f / s;
  ws[wv][lane] = w0 * inv;
  ws[wv][lane + 64] = w1 * inv;
  js[wv][lane] = j0;
  js[wv][lane + 64] = j1;
  // intra-wave LDS write->read: single-wave coherence, no barrier
  const int cbase = half * CW;
  float acc[NQ];
#pragma unroll
  for (int q = 0; q < NQ; ++q) acc[q] = 0.f;
  if (BF16G) {
#pragma unroll 8
    for (int k = 0; k < c; ++k) {
      const float wk = ws[wv][k];
      const uint32_t* hr = (const uint32_t*)(hb + (size_t)js[wv][k] * D + cbase);
      uint32_t v = hr[lane];
      acc[0] = fmaf(wk, __uint_as_float(v << 16), acc[0]);
      acc[1] = fmaf(wk, __uint_as_float(v & 0xffff0000u), acc[1]);
    }
    float2 o;
    o.x = acc[0] > 0.f ? acc[0] : expm1f(acc[0]);
    o.y = acc[1] > 0.f ? acc[1] : expm1f(acc[1]);
    *(float2*)(out + (size_t)row * D + cbase + lane * 2) = o;
  } else {
#pragma unroll 8
    for (int k = 0; k < c; ++k) {
      const float wk = ws[wv][k];
      const float* hr = h + (size_t)js[wv][k] * D + cbase;
#pragma unroll
      for (int q = 0; q < NQ; ++q) acc[q] = fmaf(wk, hr[lane + q * 64], acc[q]);
    }
    if (!NORM) {
#pragma unroll
      for (int q = 0; q < NQ; ++q) {
        float a = acc[q];
        out[(size_t)row * D + cbase + lane + q * 64] = a > 0.f ? a : expm1f(a);
      }
    } else {
      float a = acc[0];
      a = a > 0.f ? a : expm1f(a);
      float sq = a * a;
#pragma unroll
      for (int off = 32; off; off >>= 1) sq += __shfl_xor(sq, off);
      float zv = a / fmaxf(sqrtf(sq), 1e-12f);
      out[(size_t)row * 64 + lane] = zv;
      zb[(size_t)row * 64 + lane] = (__bf16)zv;
    }
  }
}

// ---------------- A_pred = sigmoid(z @ z^T) via bf16 MFMA
__global__ __launch_bounds__(256) void decoder_mfma(const __bf16* __restrict__ zb,
                                                    float* __restrict__ out) {
  const int wv = threadIdx.x >> 6, lane = threadIdx.x & 63;
  const int ib = blockIdx.y * 64 + (wv >> 1) * 32;
  const int jb = blockIdx.x * 64 + (wv & 1) * 32;
  const int l31 = lane & 31, lh = lane >> 5;
  const __bf16* Arow = zb + (size_t)(ib + l31) * 64 + lh * 8;
  const __bf16* Brow = zb + (size_t)(jb + l31) * 64 + lh * 8;
  f32x16 acc;
#pragma unroll
  for (int r = 0; r < 16; ++r) acc[r] = 0.f;
#pragma unroll
  for (int kk = 0; kk < 4; ++kk) {
    bf16x8 af = *(const bf16x8*)(Arow + kk * 16);
    bf16x8 bfv = *(const bf16x8*)(Brow + kk * 16);
    acc = __builtin_amdgcn_mfma_f32_32x32x16_bf16(af, bfv, acc, 0, 0, 0);
  }
#pragma unroll
  for (int r = 0; r < 16; ++r) {
    int rowi = (r & 3) + 8 * (r >> 2) + 4 * lh;
    float v = 1.f / (1.f + __expf(-acc[r]));
    out[(size_t)(ib + rowi) * NROW + jb + l31] = v;
  }
}

extern "C" void kernel_launch(void* const* d_in, const int* in_sizes, int n_in,
                              void* d_out, int out_size, void* d_ws, size_t ws_size,
                              hipStream_t stream) {
  const float* x   = (const float*)d_in[0];
  const float* adj = (const float*)d_in[1];
  const float* Mm  = (const float*)d_in[2];
  const float* W1  = (const float*)d_in[3];
  const float* as1 = (const float*)d_in[4];
  const float* an1 = (const float*)d_in[5];
  const float* W2  = (const float*)d_in[6];
  const float* as2 = (const float*)d_in[7];
  const float* an2 = (const float*)d_in[8];
  const float* W3  = (const float*)d_in[9];
  const float* as3 = (const float*)d_in[10];
  const float* an3 = (const float*)d_in[11];

  float* out = (float*)d_out;
  float* z = out + (size_t)NROW * NROW;

  float* wsp = (float*)d_ws;
  float* hA   = wsp;                          // [N,256] max (f32, layer-3 gather)
  float* hB   = hA + (size_t)NROW * 256;      // [N,256] max (attn outputs)
  float* sv   = hB + (size_t)NROW * 256;      // [N]
  float* nv   = sv + NROW;                    // [N]
  float* cmv  = nv + NROW;                    // [N,MAXD]
  int*   cix  = (int*)(cmv + (size_t)NROW * MAXD);  // [N,MAXD]
  int*   cct  = cix + (size_t)NROW * MAXD;    // [N]
  __bf16* zb  = (__bf16*)(cct + NROW);        // [N,64]
  __bf16* w1h = zb + (size_t)NROW * 64;       // split/transposed weights
  __bf16* w1l = w1h + 512 * 256;
  __bf16* w2h = w1l + 512 * 256;
  __bf16* w2l = w2h + 256 * 128;
  __bf16* w3h = w2l + 256 * 128;
  __bf16* w3l = w3h + 128 * 64;
  float* wsa1 = (float*)(w3l + 128 * 64);     // wsa/wna vectors
  float* wna1 = wsa1 + 512;
  float* wsa2 = wna1 + 512;
  float* wna2 = wsa2 + 256;
  float* wsa3 = wna2 + 256;
  float* wna3 = wsa3 + 128;
  __bf16* hAb = (__bf16*)(wna3 + 128);        // [N,256] bf16 gather copy

  dim3 b256(256);

  // 1. tiny prep (weight splits + wsa/wna dots)
  prep_small<<<dim3(676), b256, 0, stream>>>(
      W1, W2, W3, w1h, w1l, w2h, w2l, w3h, w3l,
      as1, an1, as2, an2, as3, an3, wsa1, wna1, wsa2, wna2, wsa3, wna3);

  // 2. gemm1: h1 = x@W1 (bf16 copy) + sv/nv
  gemm_mfma<<<dim3(NROW / 64, 4), b256, 0, stream>>>(x, w1h, w1l, wsa1, wna1, sv, nv, nullptr, hAb, 512, 256);

  // 3. attn1 fused with CSR build (writes CSR for layers 2/3)
  attn1_fused<<<dim3(NROW / 2), b256, 0, stream>>>(adj, Mm, hAb, sv, nv, hB, cct, cix, cmv);

  // 4-5. Layer 2 (bf16 gather)
  gemm_mfma<<<dim3(NROW / 64, 2), b256, 0, stream>>>(hB, w2h, w2l, wsa2, wna2, sv, nv, nullptr, hAb, 256, 128);
  attn_csr<128, 1, true, false><<<dim3(NROW / 4), b256, 0, stream>>>(nullptr, hAb, cct, cix, cmv, sv, nv, hB, nullptr);

  // 6-7. Layer 3 (f32 gather; + fused normalize -> z, zb)
  gemm_mfma<<<dim3(NROW / 64, 1), b256, 0, stream>>>(hB, w3h, w3l, wsa3, wna3, sv, nv, hA, nullptr, 128, 64);
  attn_csr<64, 1, false, true><<<dim3(NROW / 4), b256, 0, stream>>>(hA, nullptr, cct, cix, cmv, sv, nv, z, zb);

  // 8. Decoder
  decoder_mfma<<<dim3(NROW / 64, NROW / 64), b256, 0, stream>>>(zb, out);
}